// Round 13
// baseline (83.264 us; speedup 1.0000x reference)
//
#include <hip/hip_runtime.h>
#include <hip/hip_fp16.h>

#define BSZ 2
#define CIN 32
#define COUT 64
#define DD_ 8
#define HH_ 48
#define WW_ 48
#define KK 27
#define HWs (HH_*WW_)
#define DHW (DD_*HH_*WW_)
#define NBLK (BSZ*DD_*HH_)    // 768 rows
#define NTH 256               // 4 waves; block = (row, w-tile)

typedef __attribute__((ext_vector_type(8))) _Float16 half8;
typedef __attribute__((ext_vector_type(4))) float f32x4;

__device__ __forceinline__ half8 splat_h(unsigned packed, int hi) {
    union { unsigned v; _Float16 h[2]; } c; c.v = packed;
    _Float16 e = c.h[hi];
    return (half8){e, e, e, e, e, e, e, e};
}

// prep: blocks [0,NBLK): x f32 [B][Cin][D][H][W] -> xT f16 [B][D][H][W][Cin]
//       blocks [NBLK,..): w f32 (Cout,Cin,K) -> wf f16 lane-linear A-frags,
//       28 k-rows (row 27 zeroed, dummy):
//       wf[((k*4 + c)*64 + l)*8 + j] = w[c*16+(l&15)][(l>>4)*8+j][k]
__global__ void prep(const float* __restrict__ x, const float* __restrict__ wsrc,
                     _Float16* __restrict__ xT, _Float16* __restrict__ wf) {
    __shared__ float tile[CIN][WW_];
    int blk = blockIdx.x;
    if (blk < NBLK) {
        int h = blk % HH_;
        int t0 = blk / HH_;
        int d = t0 % DD_;
        int b = t0 / DD_;
        int base = d * HWs + h * WW_;
        for (int e = threadIdx.x; e < CIN * WW_; e += 256) {
            int ci = e / WW_, w = e - ci * WW_;
            tile[ci][w] = x[(size_t)(b * CIN + ci) * DHW + base + w];
        }
        __syncthreads();
        for (int e = threadIdx.x; e < CIN * WW_; e += 256) {
            int w = e >> 5, ci = e & 31;
            xT[(size_t)(b * DHW + base + w) * CIN + ci] = (_Float16)tile[ci][w];
        }
    } else {
        int idx = (blk - NBLK) * 256 + threadIdx.x;
        if (idx < 28 * 4 * 64 * 8) {
            int j = idx & 7, l = (idx >> 3) & 63, c = (idx >> 9) & 3, k = idx >> 11;
            int co = c * 16 + (l & 15), ci = (l >> 4) * 8 + j;
            wf[idx] = (k < KK) ? (_Float16)wsrc[(co * CIN + ci) * KK + k] : (_Float16)0.f;
        }
    }
}

// Main kernel: block = (row, T). Wave q covers k = q+4i (i=0..6; k=27 dummy).
// B-fragments built in registers by the consuming lane. No k-loop barriers.
__launch_bounds__(NTH, 5)
__global__ void dcn3d(const _Float16* __restrict__ xT,
                      const float* __restrict__ off, const float* __restrict__ msk,
                      const _Float16* __restrict__ wf,
                      const float* __restrict__ bias, float* __restrict__ out) {
    int blk = blockIdx.x;
    int T = blk % 3;
    int row = blk / 3;
    int h = row % HH_;
    int t0 = row / HH_;
    int d = t0 % DD_;
    int b = t0 / DD_;
    int T16 = T * 16;

    // params for this block's 16 w's: Pp[k*16 + wl], row 27 zeroed (dummy)
    __shared__ uint4 Pp[28 * 16];          // 7168 B
    __shared__ float Cred[COUT * 17];      // 4352 B (padded: bank-spread atomics)

    int tid = threadIdx.x;
    int lane = tid & 63;
    int q = tid >> 6;            // wave id = k-group
    int wl = lane & 15;
    int g = lane >> 4;           // ci granule
    int spb = d * HWs + h * WW_;

    for (int e = tid; e < COUT * 17; e += NTH) Cred[e] = 0.f;

    // ---- Phase A: params (<=2 points/thread) ----
#define PARAM(PIDX)                                                            \
    {                                                                          \
        int p = (PIDX);                                                        \
        int k = p >> 4;                                                        \
        uint4 P;                                                               \
        if (k < KK) {                                                          \
            int w = T16 + (p & 15);                                            \
            int kd = k / 9, kh2 = (k / 3) % 3, kw2 = k % 3;                    \
            int dpos = d + kd - 1;                                             \
            bool vd = (dpos >= 0) && (dpos < DD_);                             \
            int didx = min(max(dpos, 0), DD_ - 1);                             \
            int rb = didx * HWs;                                               \
            int sp = spb + w;                                                  \
            float oh = off[(b * (2 * KK) + 2 * k) * DHW + sp];                 \
            float ow = off[(b * (2 * KK) + 2 * k + 1) * DHW + sp];             \
            float m  = msk[(b * KK + k) * DHW + sp];                           \
            float vm = vd ? m : 0.f;                                           \
            float hhf = (float)(kh2 + h - 1) + oh;                             \
            float wwf = (float)(kw2 + w - 1) + ow;                             \
            float h0f = floorf(hhf), w0f = floorf(wwf);                        \
            float lh = hhf - h0f, lw = wwf - w0f;                              \
            int h0 = (int)h0f, w0 = (int)w0f, h1 = h0 + 1, w1 = w0 + 1;        \
            bool ih0 = (h0 >= 0) && (h0 < HH_), ih1 = (h1 >= 0) && (h1 < HH_); \
            bool iw0 = (w0 >= 0) && (w0 < WW_), iw1 = (w1 >= 0) && (w1 < WW_); \
            int h0c = min(max(h0, 0), HH_ - 1), h1c = min(max(h1, 0), HH_ - 1);\
            int w0c = min(max(w0, 0), WW_ - 1), w1c = min(max(w1, 0), WW_ - 1);\
            float f00 = (ih0 && iw0) ? (1.f - lh) * (1.f - lw) * vm : 0.f;     \
            float f01 = (ih0 && iw1) ? (1.f - lh) * lw * vm : 0.f;             \
            float f10 = (ih1 && iw0) ? lh * (1.f - lw) * vm : 0.f;             \
            float f11 = (ih1 && iw1) ? lh * lw * vm : 0.f;                     \
            P.x = (unsigned)(rb + h0c * WW_ + w0c)                             \
                | ((unsigned)(rb + h0c * WW_ + w1c) << 16);                    \
            P.y = (unsigned)(rb + h1c * WW_ + w0c)                             \
                | ((unsigned)(rb + h1c * WW_ + w1c) << 16);                    \
            __half2 ha = __floats2half2_rn(f00, f01);                          \
            __half2 hb = __floats2half2_rn(f10, f11);                          \
            P.z = *(const unsigned*)&ha;                                       \
            P.w = *(const unsigned*)&hb;                                       \
        } else {                                                               \
            P.x = 0u; P.y = 0u; P.z = 0u; P.w = 0u;                            \
        }                                                                      \
        Pp[p] = P;                                                             \
    }

    PARAM(tid)
    if (tid < 192) PARAM(tid + 256)
#undef PARAM
    __syncthreads();

    const _Float16* bp = xT + (size_t)b * DHW * CIN + g * 8;

    f32x4 acc0 = {0.f, 0.f, 0.f, 0.f};
    f32x4 acc1 = acc0, acc2 = acc0, acc3 = acc0;

    uint4 PA, PB;
    int kA, kB;
    half8 cA00, cA01, cA10, cA11;
    half8 cB00, cB01, cB10, cB11;

#define PRD(S, I) { k##S = q + 4 * (I); P##S = Pp[(k##S << 4) + wl]; }
#define ISS(S) { \
    c##S##00 = *(const half8*)(bp + ((size_t)(P##S.x & 0xFFFFu) << 5)); \
    c##S##01 = *(const half8*)(bp + ((size_t)(P##S.x >> 16) << 5)); \
    c##S##10 = *(const half8*)(bp + ((size_t)(P##S.y & 0xFFFFu) << 5)); \
    c##S##11 = *(const half8*)(bp + ((size_t)(P##S.y >> 16) << 5)); }
#define CMP(S) { \
    const _Float16* wp = wf + (size_t)k##S * 2048 + lane * 8; \
    half8 a0 = *(const half8*)(wp); \
    half8 a1 = *(const half8*)(wp + 512); \
    half8 a2 = *(const half8*)(wp + 1024); \
    half8 a3 = *(const half8*)(wp + 1536); \
    half8 bf = c##S##00 * splat_h(P##S.z, 0) + c##S##01 * splat_h(P##S.z, 1) \
             + c##S##10 * splat_h(P##S.w, 0) + c##S##11 * splat_h(P##S.w, 1); \
    acc0 = __builtin_amdgcn_mfma_f32_16x16x32_f16(a0, bf, acc0, 0, 0, 0); \
    acc1 = __builtin_amdgcn_mfma_f32_16x16x32_f16(a1, bf, acc1, 0, 0, 0); \
    acc2 = __builtin_amdgcn_mfma_f32_16x16x32_f16(a2, bf, acc2, 0, 0, 0); \
    acc3 = __builtin_amdgcn_mfma_f32_16x16x32_f16(a3, bf, acc3, 0, 0, 0); }

    // 7 iterations, 2-slot rotation: corners for k(i+1) in flight during CMP(i)
    PRD(A, 0) ISS(A)
    PRD(B, 1) ISS(B)
    CMP(A) PRD(A, 2) ISS(A)
    CMP(B) PRD(B, 3) ISS(B)
    CMP(A) PRD(A, 4) ISS(A)
    CMP(B) PRD(B, 5) ISS(B)
    CMP(A) PRD(A, 6) ISS(A)
    CMP(B)
    CMP(A)

#undef PRD
#undef ISS
#undef CMP

    // ---- cross-wave reduce: LDS f32 atomics into padded Cred ----
    int rg = g * 4;
#define RED(C, ACC)                                                            \
    _Pragma("unroll")                                                          \
    for (int r = 0; r < 4; ++r)                                                \
        atomicAdd(&Cred[((C) * 16 + rg + r) * 17 + wl], ACC[r]);
    RED(0, acc0) RED(1, acc1) RED(2, acc2) RED(3, acc3)
#undef RED
    __syncthreads();

    // ---- store: bias + coalesced (16 consecutive w per co) ----
    for (int e = tid; e < COUT * 16; e += NTH) {
        int co = e >> 4, w = e & 15;
        out[((b * COUT + co) * DD_ + d) * HWs + h * WW_ + T16 + w]
            = Cred[co * 17 + w] + bias[co];
    }
}

// Fallback (ws too small): straightforward fp32 path.
__global__ void dcn3d_ref(const float* __restrict__ x, const float* __restrict__ off,
                          const float* __restrict__ msk, const float* __restrict__ w,
                          const float* __restrict__ bias, float* __restrict__ out) {
    int blk = blockIdx.x;
    int h = blk % HH_;
    int t0 = blk / HH_;
    int d = t0 % DD_;
    int b = t0 / DD_;
    for (int e = threadIdx.x; e < COUT * WW_; e += 256) {
        int co = e / WW_, wo = e - co * WW_;
        float acc = bias[co];
        for (int k = 0; k < KK; ++k) {
            int kd = k / 9, kh2 = (k / 3) % 3, kw2 = k % 3;
            int dpos = d + kd - 1;
            if (dpos < 0 || dpos >= DD_) continue;
            int sp = d * HWs + h * WW_ + wo;
            float oh = off[(b * (2 * KK) + 2 * k) * DHW + sp];
            float ow = off[(b * (2 * KK) + 2 * k + 1) * DHW + sp];
            float m  = msk[(b * KK + k) * DHW + sp];
            float hhf = (float)(kh2 + h - 1) + oh;
            float wwf = (float)(kw2 + wo - 1) + ow;
            float h0f = floorf(hhf), w0f = floorf(wwf);
            float lh = hhf - h0f, lw = wwf - w0f;
            int h0 = (int)h0f, w0 = (int)w0f, h1 = h0 + 1, w1 = w0 + 1;
            bool ih0 = (h0 >= 0) && (h0 < HH_), ih1 = (h1 >= 0) && (h1 < HH_);
            bool iw0 = (w0 >= 0) && (w0 < WW_), iw1 = (w1 >= 0) && (w1 < WW_);
            int h0c = min(max(h0, 0), HH_ - 1), h1c = min(max(h1, 0), HH_ - 1);
            int w0c = min(max(w0, 0), WW_ - 1), w1c = min(max(w1, 0), WW_ - 1);
            float f00 = (ih0 && iw0) ? (1.f - lh) * (1.f - lw) * m : 0.f;
            float f01 = (ih0 && iw1) ? (1.f - lh) * lw * m : 0.f;
            float f10 = (ih1 && iw0) ? lh * (1.f - lw) * m : 0.f;
            float f11 = (ih1 && iw1) ? lh * lw * m : 0.f;
            int rb = dpos * HWs;
            for (int ci = 0; ci < CIN; ++ci) {
                const float* xp = x + (size_t)(b * CIN + ci) * DHW;
                float v = f00 * xp[rb + h0c * WW_ + w0c] + f01 * xp[rb + h0c * WW_ + w1c]
                        + f10 * xp[rb + h1c * WW_ + w0c] + f11 * xp[rb + h1c * WW_ + w1c];
                acc += w[(co * CIN + ci) * KK + k] * v;
            }
        }
        out[((b * COUT + co) * DD_ + d) * HWs + h * WW_ + wo] = acc;
    }
}

extern "C" void kernel_launch(void* const* d_in, const int* in_sizes, int n_in,
                              void* d_out, int out_size, void* d_ws, size_t ws_size,
                              hipStream_t stream) {
    const float* x    = (const float*)d_in[0];
    const float* off  = (const float*)d_in[1];
    const float* msk  = (const float*)d_in[2];
    const float* w    = (const float*)d_in[3];
    const float* bias = (const float*)d_in[4];
    float* out = (float*)d_out;

    const size_t XT_OFF   = 131072;   // wf needs 28*4*64*8*2 = 114688 B
    const size_t XT_BYTES = (size_t)BSZ * DHW * CIN * sizeof(_Float16);   // 2359296

    _Float16* wf = (_Float16*)d_ws;
    _Float16* xT = (_Float16*)((char*)d_ws + XT_OFF);
    int use = (ws_size >= XT_OFF + XT_BYTES) ? 1 : 0;

    if (use) {
        int wblocks = (28 * 4 * 64 * 8 + 255) / 256;   // 224
        prep<<<NBLK + wblocks, 256, 0, stream>>>(x, w, xT, wf);
        dcn3d<<<NBLK * 3, NTH, 0, stream>>>(xT, off, msk, wf, bias, out);
    } else {
        dcn3d_ref<<<NBLK, 256, 0, stream>>>(x, off, msk, w, bias, out);
    }
}

// Round 14
// 42.547 us; speedup vs baseline: 1.9570x; 1.9570x over previous
//
#include <hip/hip_runtime.h>
#include <hip/hip_fp16.h>

#define BSZ 2
#define CIN 32
#define COUT 64
#define DD_ 8
#define HH_ 48
#define WW_ 48
#define KK 27
#define HWs (HH_*WW_)
#define DHW (DD_*HH_*WW_)
#define NBLK (BSZ*DD_*HH_)    // 768 rows; grid = 3*NBLK (row x w-tile)
#define NTH 256               // 4 waves = 4 co-strips

typedef __attribute__((ext_vector_type(8))) _Float16 half8;
typedef __attribute__((ext_vector_type(4))) float f32x4;

__device__ __forceinline__ half8 splat_h(unsigned packed, int hi) {
    union { unsigned v; _Float16 h[2]; } c; c.v = packed;
    _Float16 e = c.h[hi];
    return (half8){e, e, e, e, e, e, e, e};
}

// Barrier without the vmcnt(0) drain __syncthreads() emits.
__device__ __forceinline__ void wg_barrier() {
    asm volatile("s_waitcnt lgkmcnt(0)" ::: "memory");
    __builtin_amdgcn_s_barrier();
    asm volatile("" ::: "memory");
}

// prep: blocks [0,NBLK): x f32 [B][Cin][D][H][W] -> xT f16 [B][D][H][W][Cin]
//       blocks [NBLK,..): w f32 (Cout,Cin,K) -> wf f16 lane-linear A-frags:
//       wf[((k*4 + c)*64 + l)*8 + j] = w[c*16+(l&15)][(l>>4)*8+j][k]
__global__ void prep(const float* __restrict__ x, const float* __restrict__ wsrc,
                     _Float16* __restrict__ xT, _Float16* __restrict__ wf) {
    __shared__ float tile[CIN][WW_];
    int blk = blockIdx.x;
    if (blk < NBLK) {
        int h = blk % HH_;
        int t0 = blk / HH_;
        int d = t0 % DD_;
        int b = t0 / DD_;
        int base = d * HWs + h * WW_;
        for (int e = threadIdx.x; e < CIN * WW_; e += 256) {
            int ci = e / WW_, w = e - ci * WW_;
            tile[ci][w] = x[(size_t)(b * CIN + ci) * DHW + base + w];
        }
        __syncthreads();
        for (int e = threadIdx.x; e < CIN * WW_; e += 256) {
            int w = e >> 5, ci = e & 31;
            xT[(size_t)(b * DHW + base + w) * CIN + ci] = (_Float16)tile[ci][w];
        }
    } else {
        int idx = (blk - NBLK) * 256 + threadIdx.x;
        if (idx < KK * 4 * 64 * 8) {
            int j = idx & 7, l = (idx >> 3) & 63, c = (idx >> 9) & 3, k = idx >> 11;
            int co = c * 16 + (l & 15), ci = (l >> 4) * 8 + j;
            wf[idx] = (_Float16)wsrc[(co * CIN + ci) * KK + k];
        }
    }
}

// Main: block = (row, T). 4 waves = 4 co-strips; wave q runs all 27 k for its
// 16co x 16w tile (acc = one f32x4, direct store). LDS-staged sampling with
// 1 task/thread/group (group = 4 k), double-buffered, 1-ahead pipeline.
__launch_bounds__(NTH, 4)
__global__ void dcn3d(const _Float16* __restrict__ xT,
                      const float* __restrict__ off, const float* __restrict__ msk,
                      const _Float16* __restrict__ wf,
                      const float* __restrict__ bias, float* __restrict__ out) {
    int blk = blockIdx.x;
    int T = blk % 3;
    int row = blk / 3;
    int h = row % HH_;
    int t0 = row / HH_;
    int d = t0 % DD_;
    int b = t0 / DD_;
    int T16 = T * 16;

    // params for this block's 16 w's: Pp[k*16 + wl]
    __shared__ uint4 Pp[KK * 16];           // 6912 B
    // blended S granules: Sh[buf][kl*64 + g*16 + wl], 16B each
    __shared__ half8 Sh[2][4 * 64];         // 2 x 4096 B  => 15104 B total

    int tid = threadIdx.x;
    int lane = tid & 63;
    int q = tid >> 6;            // wave id = co-strip
    int spb = d * HWs + h * WW_;

    // ---- Phase A: params (<=2 points/thread) ----
#define PARAM(PIDX)                                                            \
    {                                                                          \
        int p = (PIDX);                                                        \
        int k = p >> 4;                                                        \
        int wl_ = p & 15;                                                      \
        int w = T16 + wl_;                                                     \
        int kd = k / 9, kh2 = (k / 3) % 3, kw2 = k % 3;                        \
        int dpos = d + kd - 1;                                                 \
        bool vd = (dpos >= 0) && (dpos < DD_);                                 \
        int didx = min(max(dpos, 0), DD_ - 1);                                 \
        int rb = didx * HWs;                                                   \
        int sp = spb + w;                                                      \
        float oh = off[(b * (2 * KK) + 2 * k) * DHW + sp];                     \
        float ow = off[(b * (2 * KK) + 2 * k + 1) * DHW + sp];                 \
        float m  = msk[(b * KK + k) * DHW + sp];                               \
        float vm = vd ? m : 0.f;                                               \
        float hhf = (float)(kh2 + h - 1) + oh;                                 \
        float wwf = (float)(kw2 + w - 1) + ow;                                 \
        float h0f = floorf(hhf), w0f = floorf(wwf);                            \
        float lh = hhf - h0f, lw = wwf - w0f;                                  \
        int h0 = (int)h0f, w0 = (int)w0f, h1 = h0 + 1, w1 = w0 + 1;            \
        bool ih0 = (h0 >= 0) && (h0 < HH_), ih1 = (h1 >= 0) && (h1 < HH_);     \
        bool iw0 = (w0 >= 0) && (w0 < WW_), iw1 = (w1 >= 0) && (w1 < WW_);     \
        int h0c = min(max(h0, 0), HH_ - 1), h1c = min(max(h1, 0), HH_ - 1);    \
        int w0c = min(max(w0, 0), WW_ - 1), w1c = min(max(w1, 0), WW_ - 1);    \
        float f00 = (ih0 && iw0) ? (1.f - lh) * (1.f - lw) * vm : 0.f;         \
        float f01 = (ih0 && iw1) ? (1.f - lh) * lw * vm : 0.f;                 \
        float f10 = (ih1 && iw0) ? lh * (1.f - lw) * vm : 0.f;                 \
        float f11 = (ih1 && iw1) ? lh * lw * vm : 0.f;                         \
        uint4 P;                                                               \
        P.x = (unsigned)(rb + h0c * WW_ + w0c)                                 \
            | ((unsigned)(rb + h0c * WW_ + w1c) << 16);                        \
        P.y = (unsigned)(rb + h1c * WW_ + w0c)                                 \
            | ((unsigned)(rb + h1c * WW_ + w1c) << 16);                        \
        __half2 ha = __floats2half2_rn(f00, f01);                              \
        __half2 hb = __floats2half2_rn(f10, f11);                              \
        P.z = *(const unsigned*)&ha;                                           \
        P.w = *(const unsigned*)&hb;                                           \
        Pp[p] = P;                                                             \
    }

    PARAM(tid)
    if (tid < KK * 16 - NTH) PARAM(tid + NTH)
#undef PARAM
    wg_barrier();

    const _Float16* bp = xT + (size_t)b * DHW * CIN + ((tid >> 4) & 3) * 8;

    // pipeline slots (named). Task = tid: kl = tid>>6, g = (tid>>4)&3, wl = tid&15.
    half8 qA00 = {}, qA01 = {}, qA10 = {}, qA11 = {};
    half8 qB00 = {}, qB01 = {}, qB10 = {}, qB11 = {};
    unsigned wzA = 0, wwA = 0, wzB = 0, wwB = 0;

#define ISSUE(S, KB, NKg)                                                        \
    if ((NKg) == 4 || tid < (NKg) * 64) {                                        \
        int kl = tid >> 6;                                                       \
        uint4 P = Pp[((KB) + kl) * 16 + (tid & 15)];                             \
        wz##S = P.z; ww##S = P.w;                                                \
        q##S##00 = *(const half8*)(bp + ((size_t)(P.x & 0xFFFFu) << 5));         \
        q##S##01 = *(const half8*)(bp + ((size_t)(P.x >> 16) << 5));             \
        q##S##10 = *(const half8*)(bp + ((size_t)(P.y & 0xFFFFu) << 5));         \
        q##S##11 = *(const half8*)(bp + ((size_t)(P.y >> 16) << 5));             \
    }

#define WRITE(S, BUF, NKg)                                                       \
    if ((NKg) == 4 || tid < (NKg) * 64)                                          \
        Sh[BUF][tid] = q##S##00 * splat_h(wz##S, 0) + q##S##01 * splat_h(wz##S, 1)\
                     + q##S##10 * splat_h(ww##S, 0) + q##S##11 * splat_h(ww##S, 1);

    f32x4 acc = {0.f, 0.f, 0.f, 0.f};

#define GEMM(NKg, KB, BUF)                                                       \
    _Pragma("unroll")                                                            \
    for (int kl = 0; kl < (NKg); ++kl) {                                         \
        half8 a = *(const half8*)(wf + ((((KB) + kl) * 4 + q) * 64 + lane) * 8); \
        half8 bfr = Sh[BUF][kl * 64 + lane];                                     \
        acc = __builtin_amdgcn_mfma_f32_16x16x32_f16(a, bfr, acc, 0, 0, 0);      \
    }

    // ---- 7 groups {4,4,4,4,4,4,3}, 1-ahead, double-buffered ----
    ISSUE(A, 0, 4)
    WRITE(A, 0, 4)
    wg_barrier();

    ISSUE(B, 4, 4)
    GEMM(4, 0, 0)
    WRITE(B, 1, 4)
    wg_barrier();

    ISSUE(A, 8, 4)
    GEMM(4, 4, 1)
    WRITE(A, 0, 4)
    wg_barrier();

    ISSUE(B, 12, 4)
    GEMM(4, 8, 0)
    WRITE(B, 1, 4)
    wg_barrier();

    ISSUE(A, 16, 4)
    GEMM(4, 12, 1)
    WRITE(A, 0, 4)
    wg_barrier();

    ISSUE(B, 20, 4)
    GEMM(4, 16, 0)
    WRITE(B, 1, 4)
    wg_barrier();

    ISSUE(A, 24, 3)
    GEMM(4, 20, 1)
    WRITE(A, 0, 3)
    wg_barrier();

    GEMM(3, 24, 0)

#undef ISSUE
#undef WRITE
#undef GEMM

    // ---- epilogue: direct store (C: col=lane&15 -> w, row=(lane>>4)*4+r -> co) ----
    int co0 = q * 16 + (lane >> 4) * 4;
    int wcol = T16 + (lane & 15);
#pragma unroll
    for (int r = 0; r < 4; ++r)
        out[((b * COUT + co0 + r) * DD_ + d) * HWs + h * WW_ + wcol] = acc[r] + bias[co0 + r];
}

// Fallback (ws too small): straightforward fp32 path.
__global__ void dcn3d_ref(const float* __restrict__ x, const float* __restrict__ off,
                          const float* __restrict__ msk, const float* __restrict__ w,
                          const float* __restrict__ bias, float* __restrict__ out) {
    int blk = blockIdx.x;
    int h = blk % HH_;
    int t0 = blk / HH_;
    int d = t0 % DD_;
    int b = t0 / DD_;
    for (int e = threadIdx.x; e < COUT * WW_; e += 256) {
        int co = e / WW_, wo = e - co * WW_;
        float acc = bias[co];
        for (int k = 0; k < KK; ++k) {
            int kd = k / 9, kh2 = (k / 3) % 3, kw2 = k % 3;
            int dpos = d + kd - 1;
            if (dpos < 0 || dpos >= DD_) continue;
            int sp = d * HWs + h * WW_ + wo;
            float oh = off[(b * (2 * KK) + 2 * k) * DHW + sp];
            float ow = off[(b * (2 * KK) + 2 * k + 1) * DHW + sp];
            float m  = msk[(b * KK + k) * DHW + sp];
            float hhf = (float)(kh2 + h - 1) + oh;
            float wwf = (float)(kw2 + wo - 1) + ow;
            float h0f = floorf(hhf), w0f = floorf(wwf);
            float lh = hhf - h0f, lw = wwf - w0f;
            int h0 = (int)h0f, w0 = (int)w0f, h1 = h0 + 1, w1 = w0 + 1;
            bool ih0 = (h0 >= 0) && (h0 < HH_), ih1 = (h1 >= 0) && (h1 < HH_);
            bool iw0 = (w0 >= 0) && (w0 < WW_), iw1 = (w1 >= 0) && (w1 < WW_);
            int h0c = min(max(h0, 0), HH_ - 1), h1c = min(max(h1, 0), HH_ - 1);
            int w0c = min(max(w0, 0), WW_ - 1), w1c = min(max(w1, 0), WW_ - 1);
            float f00 = (ih0 && iw0) ? (1.f - lh) * (1.f - lw) * m : 0.f;
            float f01 = (ih0 && iw1) ? (1.f - lh) * lw * m : 0.f;
            float f10 = (ih1 && iw0) ? lh * (1.f - lw) * m : 0.f;
            float f11 = (ih1 && iw1) ? lh * lw * m : 0.f;
            int rb = dpos * HWs;
            for (int ci = 0; ci < CIN; ++ci) {
                const float* xp = x + (size_t)(b * CIN + ci) * DHW;
                float v = f00 * xp[rb + h0c * WW_ + w0c] + f01 * xp[rb + h0c * WW_ + w1c]
                        + f10 * xp[rb + h1c * WW_ + w0c] + f11 * xp[rb + h1c * WW_ + w1c];
                acc += w[(co * CIN + ci) * KK + k] * v;
            }
        }
        out[((b * COUT + co) * DD_ + d) * HWs + h * WW_ + wo] = acc;
    }
}

extern "C" void kernel_launch(void* const* d_in, const int* in_sizes, int n_in,
                              void* d_out, int out_size, void* d_ws, size_t ws_size,
                              hipStream_t stream) {
    const float* x    = (const float*)d_in[0];
    const float* off  = (const float*)d_in[1];
    const float* msk  = (const float*)d_in[2];
    const float* w    = (const float*)d_in[3];
    const float* bias = (const float*)d_in[4];
    float* out = (float*)d_out;

    const size_t XT_OFF   = 131072;
    const size_t XT_BYTES = (size_t)BSZ * DHW * CIN * sizeof(_Float16);   // 2359296

    _Float16* wf = (_Float16*)d_ws;
    _Float16* xT = (_Float16*)((char*)d_ws + XT_OFF);
    int use = (ws_size >= XT_OFF + XT_BYTES) ? 1 : 0;

    if (use) {
        int wblocks = (KK * 4 * 64 * 8 + 255) / 256;   // 216
        prep<<<NBLK + wblocks, 256, 0, stream>>>(x, w, xT, wf);
        dcn3d<<<NBLK * 3, NTH, 0, stream>>>(xT, off, msk, wf, bias, out);
    } else {
        dcn3d_ref<<<NBLK, 256, 0, stream>>>(x, off, msk, w, bias, out);
    }
}